// Round 9
// baseline (636.585 us; speedup 1.0000x reference)
//
#include <hip/hip_runtime.h>
#include <math.h>

// ---------------------------------------------------------------------------
// CascadeStage: B=4 N=1024 D=512 NH=8 DK=64 DFF=2048 DRAW=32 TMAX=2
// Round 9: gram_rbf bank-conflict fix (per-lane rotated inner product: the
// stride-36 xm reads were 4-way conflicted, 24% of its cycles) + __expf;
// GELU fused into the FFN1 GEMM (dual-accumulator hm+hv block, gelu in
// epilogue on fp32) — gelu_triple kernel and 67 MB/iter hm/hv traffic gone.
// done-flag can never fire (tau_k=0, H_var>0) -> both iterations run.
// ---------------------------------------------------------------------------

#define Bx   4
#define Nx   1024
#define Dx   512
#define NHx  8
#define DFFx 2048

static constexpr size_t BN  = (size_t)Bx * Nx;     // 4096
static constexpr size_t BND = BN * Dx;             // 2097152
static constexpr size_t BNF = BN * DFFx;           // 8388608
static constexpr int    DD  = Dx * Dx;             // 262144
static constexpr int    DF  = DFFx * Dx;           // 1048576

typedef __attribute__((ext_vector_type(8))) short bf16x8;
typedef __attribute__((ext_vector_type(4))) float f32x4;

__device__ __forceinline__ float sp_(float x) {
  return x > 20.f ? x : log1pf(expf(x));
}
__device__ __forceinline__ unsigned short f2b(float f) {
  unsigned u = __float_as_uint(f);
  unsigned r = (u + 0x7fffu + ((u >> 16) & 1u)) >> 16;
  return (unsigned short)r;
}
__device__ __forceinline__ float b2f(unsigned short v) {
  return __uint_as_float((unsigned)v << 16);
}

// ---------------------------------------------------------------------------
// weight conversion + small preps (merged, once per call)
// ---------------------------------------------------------------------------
__global__ __launch_bounds__(256) void cvt_weights(
    const float* __restrict__ aw_mu, const float* __restrict__ aw_rho,
    const float* __restrict__ w1_mu, const float* __restrict__ w1_rho,
    const float* __restrict__ w2_mu, const float* __restrict__ w2_rho,
    const float* __restrict__ attn_b_rho, const float* __restrict__ b1_rho,
    const float* __restrict__ b2_rho, const float* __restrict__ xraw,
    unsigned short* __restrict__ aw_bf,
    unsigned short* __restrict__ wvvar_bf,
    unsigned short* __restrict__ wovar_bf,
    unsigned short* __restrict__ w1_bf, unsigned short* __restrict__ w1var_bf,
    unsigned short* __restrict__ w2_bf, unsigned short* __restrict__ w2var_bf,
    unsigned short* __restrict__ w2comb_bf,
    float* __restrict__ bv2, float* __restrict__ bo2,
    float* __restrict__ b1v, float* __restrict__ b2v,
    float* __restrict__ sqb)
{
  int i = blockIdx.x * 256 + threadIdx.x;
  if (i < 4 * DD) {
    aw_bf[i] = f2b(aw_mu[i]);
  } else if (i < 6 * DD) {
    int j = i - 4 * DD;
    if (j < DD) { float s = sp_(aw_rho[2 * DD + j]); wvvar_bf[j] = f2b(s * s); }
    else { int k = j - DD; float s = sp_(aw_rho[3 * DD + k]); wovar_bf[k] = f2b(s * s); }
  } else if (i < 6 * DD + DF) {
    int j = i - 6 * DD;
    w1_bf[j] = f2b(w1_mu[j]);
  } else if (i < 6 * DD + 2 * DF) {
    int j = i - 6 * DD - DF;
    float s = sp_(w1_rho[j]); w1var_bf[j] = f2b(s * s);
  } else if (i < 6 * DD + 3 * DF) {
    int j = i - 6 * DD - 2 * DF;
    float m = w2_mu[j];
    float s = sp_(w2_rho[j]); float v = s * s;
    w2_bf[j] = f2b(m);
    w2var_bf[j] = f2b(v);
    w2comb_bf[j] = f2b(m * m + v);
  } else {
    int j = i - (6 * DD + 3 * DF);
    if (j < 512) {
      float s = sp_(attn_b_rho[1024 + j]); bv2[j] = s * s;
    } else if (j < 1024) {
      int k = j - 512;
      float s = sp_(attn_b_rho[1536 + k]); bo2[k] = s * s;
    } else if (j < 3072) {
      int k = j - 1024;
      float s = sp_(b1_rho[k]); b1v[k] = s * s;
    } else if (j < 3584) {
      int k = j - 3072;
      float s = sp_(b2_rho[k]); b2v[k] = s * s;
    } else if (j < 3584 + (int)BN) {
      int row = j - 3584;
      const float* x = xraw + (size_t)row * 32;
      float acc = 0.f;
      #pragma unroll
      for (int t = 0; t < 32; t++) acc += x[t] * x[t];
      sqb[row] = acc;
    }
  }
}

// ---------------------------------------------------------------------------
// rbf[h][b][n][m] = sf2[h]*exp(-d2/(2 l2[h])), bf16. Per-lane rotated inner
// product breaks the stride-36 4-way bank conflict (mm*4 mod 32 aliasing).
// ---------------------------------------------------------------------------
__global__ __launch_bounds__(256) void gram_rbf(
    const float* __restrict__ xraw, const float* __restrict__ sqb,
    const float* __restrict__ lsf, const float* __restrict__ lll,
    unsigned short* __restrict__ rbf)
{
  const int nt = blockIdx.x, mt = blockIdx.y, b = blockIdx.z;
  __shared__ float xn[64][36];
  __shared__ float xm[64][36];
  __shared__ float sn[64], sm[64];
  const int tid = threadIdx.x;
  for (int q = tid; q < 512; q += 256) {
    int rr = q >> 3, cc = (q & 7) << 2;
    *(float4*)&xn[rr][cc] =
        *(const float4*)(xraw + ((size_t)b * Nx + nt * 64 + rr) * 32 + cc);
    *(float4*)&xm[rr][cc] =
        *(const float4*)(xraw + ((size_t)b * Nx + mt * 64 + rr) * 32 + cc);
  }
  if (tid < 64) {
    sn[tid] = sqb[(size_t)b * Nx + nt * 64 + tid];
    sm[tid] = sqb[(size_t)b * Nx + mt * 64 + tid];
  }
  __syncthreads();
  const int r = tid >> 2, j = tid & 3;
  float dd[16];
  #pragma unroll
  for (int i = 0; i < 16; i++) {
    int mm = j * 16 + i;
    float g = 0.f;
    #pragma unroll
    for (int t = 0; t < 32; t++) {
      int tt = (t + mm) & 31;   // rotation: 4-way -> 2-way (free)
      g += xn[r][tt] * xm[mm][tt];
    }
    dd[i] = fmaxf(sn[r] + sm[mm] - 2.f * g, 0.f);
  }
  const int n = nt * 64 + r;
  #pragma unroll
  for (int h = 0; h < NHx; h++) {
    float sf2 = __expf(2.f * lsf[h]);
    float i2l = 0.5f * __expf(-2.f * lll[h]);
    unsigned short tmp[16];
    #pragma unroll
    for (int i = 0; i < 16; i++) tmp[i] = f2b(sf2 * __expf(-dd[i] * i2l));
    unsigned short* dst =
        rbf + ((size_t)(h * Bx + b) * Nx + n) * Nx + mt * 64 + j * 16;
    *(uint4*)dst = *(const uint4*)&tmp[0];
    *(uint4*)(dst + 8) = *(const uint4*)&tmp[8];
  }
}

// ---------------------------------------------------------------------------
// LayerNorm: one block per token, writes y and y^2 as bf16
// ---------------------------------------------------------------------------
__global__ __launch_bounds__(256) void layernorm_bf(
    const float* __restrict__ X, const float* __restrict__ g,
    const float* __restrict__ bta,
    unsigned short* __restrict__ Y, unsigned short* __restrict__ Ysq)
{
  const int row = blockIdx.x;
  const float* x = X + (size_t)row * Dx;
  const int tid = threadIdx.x;
  float v0 = x[tid], v1 = x[tid + 256];
  float s = v0 + v1;
  float ss = v0 * v0 + v1 * v1;
  #pragma unroll
  for (int o = 32; o > 0; o >>= 1) {
    s += __shfl_down(s, o);
    ss += __shfl_down(ss, o);
  }
  __shared__ float ps[4], pss[4];
  const int w = tid >> 6;
  if ((tid & 63) == 0) { ps[w] = s; pss[w] = ss; }
  __syncthreads();
  float S = ps[0] + ps[1] + ps[2] + ps[3];
  float SS = pss[0] + pss[1] + pss[2] + pss[3];
  float mean = S * (1.f / 512.f);
  float var = fmaxf(SS * (1.f / 512.f) - mean * mean, 0.f);
  float inv = rsqrtf(var + 1e-5f);
  float y0 = (v0 - mean) * inv * g[tid] + bta[tid];
  float y1 = (v1 - mean) * inv * g[tid + 256] + bta[tid + 256];
  Y[(size_t)row * Dx + tid] = f2b(y0);
  Y[(size_t)row * Dx + tid + 256] = f2b(y1);
  Ysq[(size_t)row * Dx + tid] = f2b(y0 * y0);
  Ysq[(size_t)row * Dx + tid + 256] = f2b(y1 * y1);
}

// ---------------------------------------------------------------------------
// MFMA GEMM: C[M,N] = A[M,K](bf16) @ W[N,K](bf16)^T + bias[N] (+ add_in)
// BK=64 dual half-buffers; staging via register prefetch across K-iters.
// HALFM: 64x128 tile; else 128x128. trans: write C^T bf16 (ushort4 rows).
// ---------------------------------------------------------------------------
struct GD {
  const unsigned short* A;
  const unsigned short* W;
  const float* bias;
  const float* add_in;
  void* C;
  int N;
  int trans;
};

template <bool HALFM, bool OUTBF>
__global__ __launch_bounds__(256) void gemm_mf(
    GD d0, GD d1, GD d2, int M, int K, int ldc)
{
  const GD d = (blockIdx.z == 0) ? d0 : ((blockIdx.z == 1) ? d1 : d2);
  const int n0 = blockIdx.x * 128;
  if (n0 >= d.N) return;
  constexpr int BM = HALFM ? 64 : 128;
  const int m0 = blockIdx.y * BM;

  __shared__ short As0[BM * 32];
  __shared__ short As1[BM * 32];
  __shared__ short Ws0[128 * 32];
  __shared__ short Ws1[128 * 32];

  const int tid = threadIdx.x;
  const int lane = tid & 63;
  const int wv = tid >> 6;
  const int wr = wv >> 1, wc = wv & 1;
  const int fr = lane & 15;
  const int fk = (lane >> 4) * 8;

  const int rowA = m0 + (tid >> 2);
  const int rowW = n0 + (tid >> 2);
  const int colc = (tid & 3) * 8;
  const unsigned short* gA0 = d.A + (size_t)rowA * K + colc;
  const unsigned short* gA1 = gA0 + (size_t)64 * K;
  const unsigned short* gW0 = d.W + (size_t)rowW * K + colc;
  const unsigned short* gW1 = gW0 + (size_t)64 * K;
  short* lA00 = &As0[tid * 8];
  short* lA01 = &As1[tid * 8];
  short* lA10 = &As0[(tid + 256) * 8];
  short* lA11 = &As1[(tid + 256) * 8];
  short* lW00 = &Ws0[tid * 8];
  short* lW01 = &Ws1[tid * 8];
  short* lW10 = &Ws0[(tid + 256) * 8];
  short* lW11 = &Ws1[(tid + 256) * 8];

  constexpr int MI = BM / 32;
  f32x4 acc[MI][4] = {};

  uint4 ra0, ra1, ra2, ra3, rw0, rw1, rw2, rw3;
  {
    ra0 = *(const uint4*)(gA0);
    ra1 = *(const uint4*)(gA0 + 32);
    if (!HALFM) {
      ra2 = *(const uint4*)(gA1);
      ra3 = *(const uint4*)(gA1 + 32);
    }
    rw0 = *(const uint4*)(gW0);
    rw1 = *(const uint4*)(gW0 + 32);
    rw2 = *(const uint4*)(gW1);
    rw3 = *(const uint4*)(gW1 + 32);
  }

  for (int k0 = 0; k0 < K; k0 += 64) {
    __syncthreads();
    *(uint4*)lA00 = ra0;
    *(uint4*)lA01 = ra1;
    if (!HALFM) {
      *(uint4*)lA10 = ra2;
      *(uint4*)lA11 = ra3;
    }
    *(uint4*)lW00 = rw0;
    *(uint4*)lW01 = rw1;
    *(uint4*)lW10 = rw2;
    *(uint4*)lW11 = rw3;
    __syncthreads();

    if (k0 + 64 < K) {
      int kn = k0 + 64;
      ra0 = *(const uint4*)(gA0 + kn);
      ra1 = *(const uint4*)(gA0 + kn + 32);
      if (!HALFM) {
        ra2 = *(const uint4*)(gA1 + kn);
        ra3 = *(const uint4*)(gA1 + kn + 32);
      }
      rw0 = *(const uint4*)(gW0 + kn);
      rw1 = *(const uint4*)(gW0 + kn + 32);
      rw2 = *(const uint4*)(gW1 + kn);
      rw3 = *(const uint4*)(gW1 + kn + 32);
    }

    {
      bf16x8 af[MI], bfr[4];
      #pragma unroll
      for (int mi = 0; mi < MI; mi++)
        af[mi] = *(const bf16x8*)&As0[(wr * (BM / 2) + mi * 16 + fr) * 32 + fk];
      #pragma unroll
      for (int ni = 0; ni < 4; ni++)
        bfr[ni] = *(const bf16x8*)&Ws0[(wc * 64 + ni * 16 + fr) * 32 + fk];
      #pragma unroll
      for (int mi = 0; mi < MI; mi++)
        #pragma unroll
        for (int ni = 0; ni < 4; ni++)
          acc[mi][ni] = __builtin_amdgcn_mfma_f32_16x16x32_bf16(
              af[mi], bfr[ni], acc[mi][ni], 0, 0, 0);
    }
    {
      bf16x8 af[MI], bfr[4];
      #pragma unroll
      for (int mi = 0; mi < MI; mi++)
        af[mi] = *(const bf16x8*)&As1[(wr * (BM / 2) + mi * 16 + fr) * 32 + fk];
      #pragma unroll
      for (int ni = 0; ni < 4; ni++)
        bfr[ni] = *(const bf16x8*)&Ws1[(wc * 64 + ni * 16 + fr) * 32 + fk];
      #pragma unroll
      for (int mi = 0; mi < MI; mi++)
        #pragma unroll
        for (int ni = 0; ni < 4; ni++)
          acc[mi][ni] = __builtin_amdgcn_mfma_f32_16x16x32_bf16(
              af[mi], bfr[ni], acc[mi][ni], 0, 0, 0);
    }
  }

  const int quad = lane >> 4;
  #pragma unroll
  for (int mi = 0; mi < MI; mi++) {
    #pragma unroll
    for (int ni = 0; ni < 4; ni++) {
      int col = n0 + wc * 64 + ni * 16 + fr;
      if (col >= d.N) continue;
      float bv = d.bias ? d.bias[col] : 0.f;
      int rowb = m0 + wr * (BM / 2) + mi * 16 + quad * 4;
      if (d.trans) {
        ushort4 o;
        o.x = f2b(acc[mi][ni][0] + bv);
        o.y = f2b(acc[mi][ni][1] + bv);
        o.z = f2b(acc[mi][ni][2] + bv);
        o.w = f2b(acc[mi][ni][3] + bv);
        *(ushort4*)&((unsigned short*)d.C)[(size_t)col * M + rowb] = o;
      } else {
        #pragma unroll
        for (int r = 0; r < 4; r++) {
          float v = acc[mi][ni][r] + bv;
          if (d.add_in) v += d.add_in[(size_t)(rowb + r) * ldc + col];
          if (OUTBF)
            ((unsigned short*)d.C)[(size_t)(rowb + r) * ldc + col] = f2b(v);
          else
            ((float*)d.C)[(size_t)(rowb + r) * ldc + col] = v;
        }
      }
    }
  }
}

// ---------------------------------------------------------------------------
// FFN1 GEMM with fused GELU: computes hm = lnA@w1^T + b1 and
// hv = lnB@w1var^T + b1v in one block (dual accumulators), applies
// gelu/gelu'^2 in the epilogue on fp32, writes am/am^2/av as bf16.
// M=4096 N=2048 K=512, 64x128 tile, BK=64 dual half-buffers, reg prefetch.
// ---------------------------------------------------------------------------
__global__ __launch_bounds__(256) void gemm_ffn1(
    const unsigned short* __restrict__ A1, const unsigned short* __restrict__ A2,
    const unsigned short* __restrict__ W1, const unsigned short* __restrict__ W2,
    const float* __restrict__ b1, const float* __restrict__ b2,
    unsigned short* __restrict__ am_o, unsigned short* __restrict__ am2_o,
    unsigned short* __restrict__ av_o)
{
  const int n0 = blockIdx.x * 128;
  const int m0 = blockIdx.y * 64;
  constexpr int K = 512;

  __shared__ short As0[64 * 32], As1[64 * 32];
  __shared__ short Bs0[64 * 32], Bs1[64 * 32];
  __shared__ short Ws0[128 * 32], Ws1[128 * 32];
  __shared__ short Vs0[128 * 32], Vs1[128 * 32];

  const int tid = threadIdx.x;
  const int lane = tid & 63;
  const int wv = tid >> 6;
  const int wr = wv >> 1, wc = wv & 1;
  const int fr = lane & 15;
  const int fk = (lane >> 4) * 8;

  const int rowA = m0 + (tid >> 2);
  const int rowW = n0 + (tid >> 2);
  const int colc = (tid & 3) * 8;
  const unsigned short* gA1 = A1 + (size_t)rowA * K + colc;
  const unsigned short* gA2 = A2 + (size_t)rowA * K + colc;
  const unsigned short* gW1a = W1 + (size_t)rowW * K + colc;
  const unsigned short* gW1b = gW1a + (size_t)64 * K;
  const unsigned short* gW2a = W2 + (size_t)rowW * K + colc;
  const unsigned short* gW2b = gW2a + (size_t)64 * K;

  f32x4 accA[2][4] = {};
  f32x4 accB[2][4] = {};

  uint4 ra0, ra1, rb0, rb1, rw0, rw1, rw2, rw3, rv0, rv1, rv2, rv3;
  ra0 = *(const uint4*)(gA1);      ra1 = *(const uint4*)(gA1 + 32);
  rb0 = *(const uint4*)(gA2);      rb1 = *(const uint4*)(gA2 + 32);
  rw0 = *(const uint4*)(gW1a);     rw1 = *(const uint4*)(gW1a + 32);
  rw2 = *(const uint4*)(gW1b);     rw3 = *(const uint4*)(gW1b + 32);
  rv0 = *(const uint4*)(gW2a);     rv1 = *(const uint4*)(gW2a + 32);
  rv2 = *(const uint4*)(gW2b);     rv3 = *(const uint4*)(gW2b + 32);

  for (int k0 = 0; k0 < K; k0 += 64) {
    __syncthreads();
    *(uint4*)&As0[tid * 8] = ra0;  *(uint4*)&As1[tid * 8] = ra1;
    *(uint4*)&Bs0[tid * 8] = rb0;  *(uint4*)&Bs1[tid * 8] = rb1;
    *(uint4*)&Ws0[tid * 8] = rw0;  *(uint4*)&Ws1[tid * 8] = rw1;
    *(uint4*)&Ws0[(tid + 256) * 8] = rw2;  *(uint4*)&Ws1[(tid + 256) * 8] = rw3;
    *(uint4*)&Vs0[tid * 8] = rv0;  *(uint4*)&Vs1[tid * 8] = rv1;
    *(uint4*)&Vs0[(tid + 256) * 8] = rv2;  *(uint4*)&Vs1[(tid + 256) * 8] = rv3;
    __syncthreads();

    if (k0 + 64 < K) {
      int kn = k0 + 64;
      ra0 = *(const uint4*)(gA1 + kn);  ra1 = *(const uint4*)(gA1 + kn + 32);
      rb0 = *(const uint4*)(gA2 + kn);  rb1 = *(const uint4*)(gA2 + kn + 32);
      rw0 = *(const uint4*)(gW1a + kn); rw1 = *(const uint4*)(gW1a + kn + 32);
      rw2 = *(const uint4*)(gW1b + kn); rw3 = *(const uint4*)(gW1b + kn + 32);
      rv0 = *(const uint4*)(gW2a + kn); rv1 = *(const uint4*)(gW2a + kn + 32);
      rv2 = *(const uint4*)(gW2b + kn); rv3 = *(const uint4*)(gW2b + kn + 32);
    }

    #pragma unroll
    for (int half = 0; half < 2; half++) {
      const short* As = half ? As1 : As0;
      const short* Bs = half ? Bs1 : Bs0;
      const short* Ws = half ? Ws1 : Ws0;
      const short* Vs = half ? Vs1 : Vs0;
      bf16x8 afA[2], afB[2], wf[4], vf[4];
      #pragma unroll
      for (int mi = 0; mi < 2; mi++) {
        afA[mi] = *(const bf16x8*)&As[(wr * 32 + mi * 16 + fr) * 32 + fk];
        afB[mi] = *(const bf16x8*)&Bs[(wr * 32 + mi * 16 + fr) * 32 + fk];
      }
      #pragma unroll
      for (int ni = 0; ni < 4; ni++) {
        wf[ni] = *(const bf16x8*)&Ws[(wc * 64 + ni * 16 + fr) * 32 + fk];
        vf[ni] = *(const bf16x8*)&Vs[(wc * 64 + ni * 16 + fr) * 32 + fk];
      }
      #pragma unroll
      for (int mi = 0; mi < 2; mi++)
        #pragma unroll
        for (int ni = 0; ni < 4; ni++) {
          accA[mi][ni] = __builtin_amdgcn_mfma_f32_16x16x32_bf16(
              afA[mi], wf[ni], accA[mi][ni], 0, 0, 0);
          accB[mi][ni] = __builtin_amdgcn_mfma_f32_16x16x32_bf16(
              afB[mi], vf[ni], accB[mi][ni], 0, 0, 0);
        }
    }
  }

  const int quad = lane >> 4;
  #pragma unroll
  for (int mi = 0; mi < 2; mi++) {
    #pragma unroll
    for (int ni = 0; ni < 4; ni++) {
      int col = n0 + wc * 64 + ni * 16 + fr;
      float bb1 = b1[col], bb2 = b2[col];
      int rowb = m0 + wr * 32 + mi * 16 + quad * 4;
      #pragma unroll
      for (int r = 0; r < 4; r++) {
        float hm = accA[mi][ni][r] + bb1;
        float hv = accB[mi][ni][r] + bb2;
        float phi = 0.5f * (1.f + erff(hm * 0.70710678118654752f));
        float pdf = __expf(-0.5f * hm * hm) * 0.39894228040143268f;
        float am = hm * phi;
        float gd = phi + hm * pdf;
        size_t idx = (size_t)(rowb + r) * DFFx + col;
        am_o[idx] = f2b(am);
        am2_o[idx] = f2b(am * am);
        av_o[idx] = f2b(gd * gd * hv);
      }
    }
  }
}

// ---------------------------------------------------------------------------
// MFMA flash attention: direct exp (no online rescale), reg-prefetch staging,
// O^T operand swap, P and P^2 staged through LDS (independent ds_reads).
// ---------------------------------------------------------------------------
__global__ __launch_bounds__(256) void flash_mfma(
    const unsigned short* __restrict__ QK,
    const unsigned short* __restrict__ VT,
    const unsigned short* __restrict__ rbf,
    unsigned short* __restrict__ ctx_bf, unsigned short* __restrict__ ctxsq_bf,
    float* __restrict__ vta)
{
  const int qt = blockIdx.x, h = blockIdx.y, b = blockIdx.z;
  const int q0 = qt * 64;
  const int tid = threadIdx.x;
  const int w = tid >> 6;
  const int lane = tid & 63;
  const int fr = lane & 15;
  const int quad = lane >> 4;

  __shared__ unsigned short Kt[64 * 72];
  __shared__ unsigned short VtT[64 * 72];
  __shared__ unsigned short VvT[64 * 72];
  __shared__ unsigned short Pt[64 * 72];
  __shared__ unsigned short P2t[64 * 72];
  __shared__ float lred[4][16];

  bf16x8 qa0, qa1;
  {
    const unsigned short* qp =
        QK + ((size_t)(b * Nx + q0 + w * 16 + fr)) * 1024 + h * 64 + quad * 8;
    qa0 = *(const bf16x8*)qp;
    qa1 = *(const bf16x8*)(qp + 32);
  }

  float lsum[4] = {0.f, 0.f, 0.f, 0.f};
  f32x4 accO[4] = {};
  f32x4 accW[4] = {};

  const unsigned short* kg = QK + ((size_t)b * Nx) * 1024 + 512 + h * 64;
  const unsigned short* vg = VT + (size_t)(h * 64) * BN + b * Nx;
  const unsigned short* ug = VT + (size_t)(512 + h * 64) * BN + b * Nx;
  const unsigned short* rb =
      rbf + ((size_t)(h * Bx + b) * Nx + q0 + w * 16 + quad * 4) * Nx;

  const int a0 = tid >> 3;
  const int c8 = (tid & 7) * 8;

  uint4 pk0, pk1, pv0, pv1, pu0, pu1;
  pk0 = *(const uint4*)(kg + (size_t)a0 * 1024 + c8);
  pk1 = *(const uint4*)(kg + (size_t)(a0 + 32) * 1024 + c8);
  pv0 = *(const uint4*)(vg + (size_t)a0 * BN + c8);
  pv1 = *(const uint4*)(vg + (size_t)(a0 + 32) * BN + c8);
  pu0 = *(const uint4*)(ug + (size_t)a0 * BN + c8);
  pu1 = *(const uint4*)(ug + (size_t)(a0 + 32) * BN + c8);

  for (int mt = 0; mt < 16; mt++) {
    __syncthreads();
    *(uint4*)&Kt[a0 * 72 + c8] = pk0;
    *(uint4*)&Kt[(a0 + 32) * 72 + c8] = pk1;
    *(uint4*)&VtT[a0 * 72 + c8] = pv0;
    *(uint4*)&VtT[(a0 + 32) * 72 + c8] = pv1;
    *(uint4*)&VvT[a0 * 72 + c8] = pu0;
    *(uint4*)&VvT[(a0 + 32) * 72 + c8] = pu1;
    __syncthreads();

    if (mt + 1 < 16) {
      const int n1 = (mt + 1) * 64;
      pk0 = *(const uint4*)(kg + (size_t)(n1 + a0) * 1024 + c8);
      pk1 = *(const uint4*)(kg + (size_t)(n1 + a0 + 32) * 1024 + c8);
      pv0 = *(const uint4*)(vg + (size_t)a0 * BN + n1 + c8);
      pv1 = *(const uint4*)(vg + (size_t)(a0 + 32) * BN + n1 + c8);
      pu0 = *(const uint4*)(ug + (size_t)a0 * BN + n1 + c8);
      pu1 = *(const uint4*)(ug + (size_t)(a0 + 32) * BN + n1 + c8);
    }

    f32x4 accS[4] = {};
    #pragma unroll
    for (int ni = 0; ni < 4; ni++) {
      bf16x8 b0 = *(const bf16x8*)&Kt[(ni * 16 + fr) * 72 + quad * 8];
      bf16x8 b1 = *(const bf16x8*)&Kt[(ni * 16 + fr) * 72 + 32 + quad * 8];
      accS[ni] = __builtin_amdgcn_mfma_f32_16x16x32_bf16(qa0, b0, accS[ni], 0, 0, 0);
      accS[ni] = __builtin_amdgcn_mfma_f32_16x16x32_bf16(qa1, b1, accS[ni], 0, 0, 0);
    }

    const int m0 = mt * 64;
    #pragma unroll
    for (int reg = 0; reg < 4; reg++) {
      const unsigned short* rr = rb + (size_t)reg * Nx + m0;
      int rowb = (w * 16 + quad * 4 + reg) * 72;
      #pragma unroll
      for (int ni = 0; ni < 4; ni++) {
        float pv = __expf(accS[ni][reg] * 0.125f + b2f(rr[ni * 16 + fr]));
        lsum[reg] += pv;
        Pt[rowb + ni * 16 + fr] = f2b(pv);
        P2t[rowb + ni * 16 + fr] = f2b(pv * pv);
      }
    }
    __syncthreads();

    #pragma unroll
    for (int ks = 0; ks < 2; ks++) {
      bf16x8 pa  = *(const bf16x8*)&Pt[(w * 16 + fr) * 72 + ks * 32 + quad * 8];
      bf16x8 p2a = *(const bf16x8*)&P2t[(w * 16 + fr) * 72 + ks * 32 + quad * 8];
      #pragma unroll
      for (int ni = 0; ni < 4; ni++) {
        bf16x8 vb = *(const bf16x8*)&VtT[(ni * 16 + fr) * 72 + ks * 32 + quad * 8];
        bf16x8 ub = *(const bf16x8*)&VvT[(ni * 16 + fr) * 72 + ks * 32 + quad * 8];
        accO[ni] = __builtin_amdgcn_mfma_f32_16x16x32_bf16(vb, pa, accO[ni], 0, 0, 0);
        accW[ni] = __builtin_amdgcn_mfma_f32_16x16x32_bf16(ub, p2a, accW[ni], 0, 0, 0);
      }
    }
  }

  #pragma unroll
  for (int reg = 0; reg < 4; reg++) {
    float t = lsum[reg];
    t += __shfl_xor(t, 1);
    t += __shfl_xor(t, 2);
    t += __shfl_xor(t, 4);
    t += __shfl_xor(t, 8);
    lsum[reg] = t;
  }
  if (fr == 0) {
    #pragma unroll
    for (int reg = 0; reg < 4; reg++) lred[w][quad * 4 + reg] = lsum[reg];
  }
  __syncthreads();
  float invl = 1.f / lred[w][fr];
  float invl2 = invl * invl;

  size_t row = (size_t)b * Nx + q0 + w * 16 + fr;
  #pragma unroll
  for (int ni = 0; ni < 4; ni++) {
    int dkb = h * 64 + ni * 16 + quad * 4;
    ushort4 oc, oc2;
    float4 ov;
    float c0 = accO[ni][0] * invl, c1 = accO[ni][1] * invl;
    float c2 = accO[ni][2] * invl, c3 = accO[ni][3] * invl;
    oc.x = f2b(c0); oc.y = f2b(c1); oc.z = f2b(c2); oc.w = f2b(c3);
    oc2.x = f2b(c0 * c0); oc2.y = f2b(c1 * c1);
    oc2.z = f2b(c2 * c2); oc2.w = f2b(c3 * c3);
    ov.x = accW[ni][0] * invl2; ov.y = accW[ni][1] * invl2;
    ov.z = accW[ni][2] * invl2; ov.w = accW[ni][3] * invl2;
    *(ushort4*)&ctx_bf[row * Dx + dkb] = oc;
    *(ushort4*)&ctxsq_bf[row * Dx + dkb] = oc2;
    *(float4*)&vta[row * Dx + dkb] = ov;
  }
}

// ---------------------------------------------------------------------------
// combine (x4 vectorized): F = Hb+fm (fused); fva = avar+ovd (fused)
// ---------------------------------------------------------------------------
__global__ __launch_bounds__(256) void combine_k(
    const float* __restrict__ Hin, const float* __restrict__ Hvin,
    float* __restrict__ Hout, float* __restrict__ Hvout,
    const float* __restrict__ F, const float* __restrict__ fva,
    const float* __restrict__ vc, const float* __restrict__ lg)
{
  size_t i = ((size_t)blockIdx.x * 256 + threadIdx.x) * 4;
  float g1 = sp_(lg[0]), g2 = sp_(lg[1]), g3 = sp_(lg[2]), g4 = sp_(lg[3]);
  float s12 = g1 + g2, s34 = g3 + g4;
  float alpha = g1 / s12, beta = g3 / s34;
  float Va = g1 * g2 / (s12 * s12 * (s12 + 1.f));
  float Vb = g3 * g4 / (s34 * s34 * (s34 + 1.f));
  float4 h4 = *(const float4*)&Hin[i];
  float4 hv4 = *(const float4*)&Hvin[i];
  float4 F4 = *(const float4*)&F[i];
  float4 a4 = *(const float4*)&fva[i];
  float4 c4 = *(const float4*)&vc[i];
  float* hp = (float*)&h4; float* vp = (float*)&hv4;
  const float* Fp = (const float*)&F4; const float* ap = (const float*)&a4;
  const float* cp = (const float*)&c4;
  float4 ho, vo;
  float* hop = (float*)&ho; float* vop = (float*)&vo;
  #pragma unroll
  for (int j = 0; j < 4; j++) {
    float h = hp[j], hv = vp[j];
    float Fm = Fp[j];
    float Fv = ap[j] + cp[j];
    hop[j] = alpha * h + beta * Fm;
    vop[j] = alpha * alpha * hv + beta * beta * Fv + Va * h * h + Vb * Fm * Fm +
             Va * hv + Vb * Fv;
  }
  *(float4*)&Hout[i] = ho;
  *(float4*)&Hvout[i] = vo;
}

// ---------------------------------------------------------------------------
// launch
// ---------------------------------------------------------------------------
extern "C" void kernel_launch(void* const* d_in, const int* in_sizes, int n_in,
                              void* d_out, int out_size, void* d_ws, size_t ws_size,
                              hipStream_t stream)
{
  const float* H_in   = (const float*)d_in[0];
  const float* Hv_in  = (const float*)d_in[1];
  const float* x_raw  = (const float*)d_in[2];
  const float* aw_mu  = (const float*)d_in[4];
  const float* aw_rho = (const float*)d_in[5];
  const float* ab_mu  = (const float*)d_in[6];
  const float* ab_rho = (const float*)d_in[7];
  const float* w1_mu  = (const float*)d_in[8];
  const float* w1_rho = (const float*)d_in[9];
  const float* b1_mu  = (const float*)d_in[10];
  const float* b1_rho = (const float*)d_in[11];
  const float* w2_mu  = (const float*)d_in[12];
  const float* w2_rho = (const float*)d_in[13];
  const float* b2_mu  = (const float*)d_in[14];
  const float* b2_rho = (const float*)d_in[15];
  const float* ln1_g  = (const float*)d_in[16];
  const float* ln1_b  = (const float*)d_in[17];
  const float* ln2_g  = (const float*)d_in[18];
  const float* ln2_b  = (const float*)d_in[19];
  const float* lsf    = (const float*)d_in[20];
  const float* lll    = (const float*)d_in[21];
  const float* lgam   = (const float*)d_in[22];

  float* Hout = (float*)d_out;
  float* Hvar = (float*)d_out + BND;

  float* ws = (float*)d_ws;
  size_t off = 0;
  auto allocf = [&](size_t n) {
    float* p = ws + off; off += (n + 7) & ~(size_t)7; return p;
  };
  auto allocus = [&](size_t n) {
    return (unsigned short*)allocf((n + 1) / 2);
  };
  unsigned short* rbf = allocus((size_t)NHx * Bx * Nx * Nx);   // 67 MB
  float* vta = allocf(BND);
  float* Hb  = allocf(BND);
  float* fva = allocf(BND);
  float* vc  = allocf(BND);
  unsigned short* QKb = allocus(BN * 1024);
  unsigned short* VTb = allocus((size_t)1024 * BN);
  unsigned short* lnA = allocus(BND);
  unsigned short* lnB = allocus(BND);
  unsigned short* am_bf  = allocus(BNF);
  unsigned short* am2_bf = allocus(BNF);
  unsigned short* av_bf  = allocus(BNF);
  unsigned short* aw_bf     = allocus(4 * DD);
  unsigned short* wvvar_bf  = allocus(DD);
  unsigned short* wovar_bf  = allocus(DD);
  unsigned short* w1_bf     = allocus(DF);
  unsigned short* w1var_bf  = allocus(DF);
  unsigned short* w2_bf     = allocus(DF);
  unsigned short* w2var_bf  = allocus(DF);
  unsigned short* w2comb_bf = allocus(DF);
  float* bv2 = allocf(512);
  float* bo2 = allocf(512);
  float* b1v = allocf(2048);
  float* b2v = allocf(512);
  float* sqb = allocf(BN);
  (void)ws_size; (void)in_sizes; (void)n_in; (void)out_size;

  {
    int tot = 6 * DD + 3 * DF + 3584 + (int)BN;
    cvt_weights<<<(tot + 255) / 256, 256, 0, stream>>>(
        aw_mu, aw_rho, w1_mu, w1_rho, w2_mu, w2_rho,
        ab_rho, b1_rho, b2_rho, x_raw,
        aw_bf, wvvar_bf, wovar_bf, w1_bf, w1var_bf, w2_bf, w2var_bf,
        w2comb_bf, bv2, bo2, b1v, b2v, sqb);
  }
  gram_rbf<<<dim3(16, 16, Bx), 256, 0, stream>>>(x_raw, sqb, lsf, lll, rbf);

  const int M = (int)BN;
  GD dz = {nullptr, nullptr, nullptr, nullptr, nullptr, 0, 0};

  const float* Hsrc  = H_in;
  const float* Hvsrc = Hv_in;

  for (int t = 0; t < 2; t++) {   // TMAX (early-exit statically dead)
    // ---- attention half ----
    layernorm_bf<<<(int)BN, 256, 0, stream>>>(Hsrc, ln1_g, ln1_b, lnA, lnB);
    {
      GD dqk = {lnA, aw_bf, ab_mu, nullptr, (void*)QKb, 1024, 0};
      GD dv  = {lnA, aw_bf + 2 * (size_t)DD, ab_mu + 1024, nullptr,
                (void*)VTb, 512, 1};
      GD dvv = {lnB, wvvar_bf, bv2, nullptr,
                (void*)(VTb + (size_t)512 * BN), 512, 1};
      gemm_mf<false, true><<<dim3(8, 32, 3), 256, 0, stream>>>(
          dqk, dv, dvv, M, 512, 1024);
    }
    flash_mfma<<<dim3(Nx / 64, NHx, Bx), 256, 0, stream>>>(
        QKb, VTb, rbf, lnA, lnB, vta);
    {
      GD d_om = {lnA, aw_bf + 3 * (size_t)DD, ab_mu + 1536, Hsrc, (void*)Hb,
                 512, 0};
      GD d_ov = {lnB, wovar_bf, bo2, vta, (void*)vta, 512, 0};
      gemm_mf<true, false><<<dim3(4, 64, 2), 256, 0, stream>>>(
          d_om, d_ov, dz, M, 512, 512);
    }

    // ---- FFN half ----
    layernorm_bf<<<(int)BN, 256, 0, stream>>>(Hb, ln2_g, ln2_b, lnA, lnB);
    gemm_ffn1<<<dim3(16, 64), 256, 0, stream>>>(
        lnA, lnB, w1_bf, w1var_bf, b1_mu, b1v, am_bf, am2_bf, av_bf);
    {
      GD d_fm  = {am_bf, w2_bf, b2_mu, Hb, (void*)Hb, 512, 0};    // F = Hb+fm
      GD d_ovd = {am2_bf, w2var_bf, b2v, vta, (void*)fva, 512, 0}; // avar+ovd
      GD d_vc  = {av_bf, w2comb_bf, nullptr, nullptr, (void*)vc, 512, 0};
      gemm_mf<true, false><<<dim3(4, 64, 3), 256, 0, stream>>>(
          d_fm, d_ovd, d_vc, M, 2048, 512);
    }
    combine_k<<<(int)(BND / (256 * 4)), 256, 0, stream>>>(
        Hsrc, Hvsrc, Hout, Hvar, Hb, fva, vc, lgam);

    Hsrc = Hout;
    Hvsrc = Hvar;
  }
}

// Round 10
// 578.065 us; speedup vs baseline: 1.1012x; 1.1012x over previous
//
#include <hip/hip_runtime.h>
#include <math.h>

// ---------------------------------------------------------------------------
// CascadeStage: B=4 N=1024 D=512 NH=8 DK=64 DFF=2048 DRAW=32 TMAX=2
// Round 10: revert flash's __expf -> expf (round 9 lesson: the expf VALU
// block is what hides the prefetch HBM latency; __expf shrank it 5x, the
// compiler sank the prefetch loads (VGPR 100->72) and flash went 55->85us).
// Keep round-9 wins: gram_rbf conflict fix (+__expf there), fused FFN1+GELU.
// done-flag can never fire (tau_k=0, H_var>0) -> both iterations run.
// ---------------------------------------------------------------------------

#define Bx   4
#define Nx   1024
#define Dx   512
#define NHx  8
#define DFFx 2048

static constexpr size_t BN  = (size_t)Bx * Nx;     // 4096
static constexpr size_t BND = BN * Dx;             // 2097152
static constexpr size_t BNF = BN * DFFx;           // 8388608
static constexpr int    DD  = Dx * Dx;             // 262144
static constexpr int    DF  = DFFx * Dx;           // 1048576

typedef __attribute__((ext_vector_type(8))) short bf16x8;
typedef __attribute__((ext_vector_type(4))) float f32x4;

__device__ __forceinline__ float sp_(float x) {
  return x > 20.f ? x : log1pf(expf(x));
}
__device__ __forceinline__ unsigned short f2b(float f) {
  unsigned u = __float_as_uint(f);
  unsigned r = (u + 0x7fffu + ((u >> 16) & 1u)) >> 16;
  return (unsigned short)r;
}
__device__ __forceinline__ float b2f(unsigned short v) {
  return __uint_as_float((unsigned)v << 16);
}

// ---------------------------------------------------------------------------
// weight conversion + small preps (merged, once per call)
// ---------------------------------------------------------------------------
__global__ __launch_bounds__(256) void cvt_weights(
    const float* __restrict__ aw_mu, const float* __restrict__ aw_rho,
    const float* __restrict__ w1_mu, const float* __restrict__ w1_rho,
    const float* __restrict__ w2_mu, const float* __restrict__ w2_rho,
    const float* __restrict__ attn_b_rho, const float* __restrict__ b1_rho,
    const float* __restrict__ b2_rho, const float* __restrict__ xraw,
    unsigned short* __restrict__ aw_bf,
    unsigned short* __restrict__ wvvar_bf,
    unsigned short* __restrict__ wovar_bf,
    unsigned short* __restrict__ w1_bf, unsigned short* __restrict__ w1var_bf,
    unsigned short* __restrict__ w2_bf, unsigned short* __restrict__ w2var_bf,
    unsigned short* __restrict__ w2comb_bf,
    float* __restrict__ bv2, float* __restrict__ bo2,
    float* __restrict__ b1v, float* __restrict__ b2v,
    float* __restrict__ sqb)
{
  int i = blockIdx.x * 256 + threadIdx.x;
  if (i < 4 * DD) {
    aw_bf[i] = f2b(aw_mu[i]);
  } else if (i < 6 * DD) {
    int j = i - 4 * DD;
    if (j < DD) { float s = sp_(aw_rho[2 * DD + j]); wvvar_bf[j] = f2b(s * s); }
    else { int k = j - DD; float s = sp_(aw_rho[3 * DD + k]); wovar_bf[k] = f2b(s * s); }
  } else if (i < 6 * DD + DF) {
    int j = i - 6 * DD;
    w1_bf[j] = f2b(w1_mu[j]);
  } else if (i < 6 * DD + 2 * DF) {
    int j = i - 6 * DD - DF;
    float s = sp_(w1_rho[j]); w1var_bf[j] = f2b(s * s);
  } else if (i < 6 * DD + 3 * DF) {
    int j = i - 6 * DD - 2 * DF;
    float m = w2_mu[j];
    float s = sp_(w2_rho[j]); float v = s * s;
    w2_bf[j] = f2b(m);
    w2var_bf[j] = f2b(v);
    w2comb_bf[j] = f2b(m * m + v);
  } else {
    int j = i - (6 * DD + 3 * DF);
    if (j < 512) {
      float s = sp_(attn_b_rho[1024 + j]); bv2[j] = s * s;
    } else if (j < 1024) {
      int k = j - 512;
      float s = sp_(attn_b_rho[1536 + k]); bo2[k] = s * s;
    } else if (j < 3072) {
      int k = j - 1024;
      float s = sp_(b1_rho[k]); b1v[k] = s * s;
    } else if (j < 3584) {
      int k = j - 3072;
      float s = sp_(b2_rho[k]); b2v[k] = s * s;
    } else if (j < 3584 + (int)BN) {
      int row = j - 3584;
      const float* x = xraw + (size_t)row * 32;
      float acc = 0.f;
      #pragma unroll
      for (int t = 0; t < 32; t++) acc += x[t] * x[t];
      sqb[row] = acc;
    }
  }
}

// ---------------------------------------------------------------------------
// rbf[h][b][n][m] = sf2[h]*exp(-d2/(2 l2[h])), bf16. Per-lane rotated inner
// product breaks the stride-36 4-way bank conflict (mm*4 mod 32 aliasing).
// ---------------------------------------------------------------------------
__global__ __launch_bounds__(256) void gram_rbf(
    const float* __restrict__ xraw, const float* __restrict__ sqb,
    const float* __restrict__ lsf, const float* __restrict__ lll,
    unsigned short* __restrict__ rbf)
{
  const int nt = blockIdx.x, mt = blockIdx.y, b = blockIdx.z;
  __shared__ float xn[64][36];
  __shared__ float xm[64][36];
  __shared__ float sn[64], sm[64];
  const int tid = threadIdx.x;
  for (int q = tid; q < 512; q += 256) {
    int rr = q >> 3, cc = (q & 7) << 2;
    *(float4*)&xn[rr][cc] =
        *(const float4*)(xraw + ((size_t)b * Nx + nt * 64 + rr) * 32 + cc);
    *(float4*)&xm[rr][cc] =
        *(const float4*)(xraw + ((size_t)b * Nx + mt * 64 + rr) * 32 + cc);
  }
  if (tid < 64) {
    sn[tid] = sqb[(size_t)b * Nx + nt * 64 + tid];
    sm[tid] = sqb[(size_t)b * Nx + mt * 64 + tid];
  }
  __syncthreads();
  const int r = tid >> 2, j = tid & 3;
  float dd[16];
  #pragma unroll
  for (int i = 0; i < 16; i++) {
    int mm = j * 16 + i;
    float g = 0.f;
    #pragma unroll
    for (int t = 0; t < 32; t++) {
      int tt = (t + mm) & 31;   // rotation: 4-way -> 2-way (free)
      g += xn[r][tt] * xm[mm][tt];
    }
    dd[i] = fmaxf(sn[r] + sm[mm] - 2.f * g, 0.f);
  }
  const int n = nt * 64 + r;
  #pragma unroll
  for (int h = 0; h < NHx; h++) {
    float sf2 = __expf(2.f * lsf[h]);
    float i2l = 0.5f * __expf(-2.f * lll[h]);
    unsigned short tmp[16];
    #pragma unroll
    for (int i = 0; i < 16; i++) tmp[i] = f2b(sf2 * __expf(-dd[i] * i2l));
    unsigned short* dst =
        rbf + ((size_t)(h * Bx + b) * Nx + n) * Nx + mt * 64 + j * 16;
    *(uint4*)dst = *(const uint4*)&tmp[0];
    *(uint4*)(dst + 8) = *(const uint4*)&tmp[8];
  }
}

// ---------------------------------------------------------------------------
// LayerNorm: one block per token, writes y and y^2 as bf16
// ---------------------------------------------------------------------------
__global__ __launch_bounds__(256) void layernorm_bf(
    const float* __restrict__ X, const float* __restrict__ g,
    const float* __restrict__ bta,
    unsigned short* __restrict__ Y, unsigned short* __restrict__ Ysq)
{
  const int row = blockIdx.x;
  const float* x = X + (size_t)row * Dx;
  const int tid = threadIdx.x;
  float v0 = x[tid], v1 = x[tid + 256];
  float s = v0 + v1;
  float ss = v0 * v0 + v1 * v1;
  #pragma unroll
  for (int o = 32; o > 0; o >>= 1) {
    s += __shfl_down(s, o);
    ss += __shfl_down(ss, o);
  }
  __shared__ float ps[4], pss[4];
  const int w = tid >> 6;
  if ((tid & 63) == 0) { ps[w] = s; pss[w] = ss; }
  __syncthreads();
  float S = ps[0] + ps[1] + ps[2] + ps[3];
  float SS = pss[0] + pss[1] + pss[2] + pss[3];
  float mean = S * (1.f / 512.f);
  float var = fmaxf(SS * (1.f / 512.f) - mean * mean, 0.f);
  float inv = rsqrtf(var + 1e-5f);
  float y0 = (v0 - mean) * inv * g[tid] + bta[tid];
  float y1 = (v1 - mean) * inv * g[tid + 256] + bta[tid + 256];
  Y[(size_t)row * Dx + tid] = f2b(y0);
  Y[(size_t)row * Dx + tid + 256] = f2b(y1);
  Ysq[(size_t)row * Dx + tid] = f2b(y0 * y0);
  Ysq[(size_t)row * Dx + tid + 256] = f2b(y1 * y1);
}

// ---------------------------------------------------------------------------
// MFMA GEMM: C[M,N] = A[M,K](bf16) @ W[N,K](bf16)^T + bias[N] (+ add_in)
// BK=64 dual half-buffers; staging via register prefetch across K-iters.
// HALFM: 64x128 tile; else 128x128. trans: write C^T bf16 (ushort4 rows).
// ---------------------------------------------------------------------------
struct GD {
  const unsigned short* A;
  const unsigned short* W;
  const float* bias;
  const float* add_in;
  void* C;
  int N;
  int trans;
};

template <bool HALFM, bool OUTBF>
__global__ __launch_bounds__(256) void gemm_mf(
    GD d0, GD d1, GD d2, int M, int K, int ldc)
{
  const GD d = (blockIdx.z == 0) ? d0 : ((blockIdx.z == 1) ? d1 : d2);
  const int n0 = blockIdx.x * 128;
  if (n0 >= d.N) return;
  constexpr int BM = HALFM ? 64 : 128;
  const int m0 = blockIdx.y * BM;

  __shared__ short As0[BM * 32];
  __shared__ short As1[BM * 32];
  __shared__ short Ws0[128 * 32];
  __shared__ short Ws1[128 * 32];

  const int tid = threadIdx.x;
  const int lane = tid & 63;
  const int wv = tid >> 6;
  const int wr = wv >> 1, wc = wv & 1;
  const int fr = lane & 15;
  const int fk = (lane >> 4) * 8;

  const int rowA = m0 + (tid >> 2);
  const int rowW = n0 + (tid >> 2);
  const int colc = (tid & 3) * 8;
  const unsigned short* gA0 = d.A + (size_t)rowA * K + colc;
  const unsigned short* gA1 = gA0 + (size_t)64 * K;
  const unsigned short* gW0 = d.W + (size_t)rowW * K + colc;
  const unsigned short* gW1 = gW0 + (size_t)64 * K;
  short* lA00 = &As0[tid * 8];
  short* lA01 = &As1[tid * 8];
  short* lA10 = &As0[(tid + 256) * 8];
  short* lA11 = &As1[(tid + 256) * 8];
  short* lW00 = &Ws0[tid * 8];
  short* lW01 = &Ws1[tid * 8];
  short* lW10 = &Ws0[(tid + 256) * 8];
  short* lW11 = &Ws1[(tid + 256) * 8];

  constexpr int MI = BM / 32;
  f32x4 acc[MI][4] = {};

  uint4 ra0, ra1, ra2, ra3, rw0, rw1, rw2, rw3;
  {
    ra0 = *(const uint4*)(gA0);
    ra1 = *(const uint4*)(gA0 + 32);
    if (!HALFM) {
      ra2 = *(const uint4*)(gA1);
      ra3 = *(const uint4*)(gA1 + 32);
    }
    rw0 = *(const uint4*)(gW0);
    rw1 = *(const uint4*)(gW0 + 32);
    rw2 = *(const uint4*)(gW1);
    rw3 = *(const uint4*)(gW1 + 32);
  }

  for (int k0 = 0; k0 < K; k0 += 64) {
    __syncthreads();
    *(uint4*)lA00 = ra0;
    *(uint4*)lA01 = ra1;
    if (!HALFM) {
      *(uint4*)lA10 = ra2;
      *(uint4*)lA11 = ra3;
    }
    *(uint4*)lW00 = rw0;
    *(uint4*)lW01 = rw1;
    *(uint4*)lW10 = rw2;
    *(uint4*)lW11 = rw3;
    __syncthreads();

    if (k0 + 64 < K) {
      int kn = k0 + 64;
      ra0 = *(const uint4*)(gA0 + kn);
      ra1 = *(const uint4*)(gA0 + kn + 32);
      if (!HALFM) {
        ra2 = *(const uint4*)(gA1 + kn);
        ra3 = *(const uint4*)(gA1 + kn + 32);
      }
      rw0 = *(const uint4*)(gW0 + kn);
      rw1 = *(const uint4*)(gW0 + kn + 32);
      rw2 = *(const uint4*)(gW1 + kn);
      rw3 = *(const uint4*)(gW1 + kn + 32);
    }

    {
      bf16x8 af[MI], bfr[4];
      #pragma unroll
      for (int mi = 0; mi < MI; mi++)
        af[mi] = *(const bf16x8*)&As0[(wr * (BM / 2) + mi * 16 + fr) * 32 + fk];
      #pragma unroll
      for (int ni = 0; ni < 4; ni++)
        bfr[ni] = *(const bf16x8*)&Ws0[(wc * 64 + ni * 16 + fr) * 32 + fk];
      #pragma unroll
      for (int mi = 0; mi < MI; mi++)
        #pragma unroll
        for (int ni = 0; ni < 4; ni++)
          acc[mi][ni] = __builtin_amdgcn_mfma_f32_16x16x32_bf16(
              af[mi], bfr[ni], acc[mi][ni], 0, 0, 0);
    }
    {
      bf16x8 af[MI], bfr[4];
      #pragma unroll
      for (int mi = 0; mi < MI; mi++)
        af[mi] = *(const bf16x8*)&As1[(wr * (BM / 2) + mi * 16 + fr) * 32 + fk];
      #pragma unroll
      for (int ni = 0; ni < 4; ni++)
        bfr[ni] = *(const bf16x8*)&Ws1[(wc * 64 + ni * 16 + fr) * 32 + fk];
      #pragma unroll
      for (int mi = 0; mi < MI; mi++)
        #pragma unroll
        for (int ni = 0; ni < 4; ni++)
          acc[mi][ni] = __builtin_amdgcn_mfma_f32_16x16x32_bf16(
              af[mi], bfr[ni], acc[mi][ni], 0, 0, 0);
    }
  }

  const int quad = lane >> 4;
  #pragma unroll
  for (int mi = 0; mi < MI; mi++) {
    #pragma unroll
    for (int ni = 0; ni < 4; ni++) {
      int col = n0 + wc * 64 + ni * 16 + fr;
      if (col >= d.N) continue;
      float bv = d.bias ? d.bias[col] : 0.f;
      int rowb = m0 + wr * (BM / 2) + mi * 16 + quad * 4;
      if (d.trans) {
        ushort4 o;
        o.x = f2b(acc[mi][ni][0] + bv);
        o.y = f2b(acc[mi][ni][1] + bv);
        o.z = f2b(acc[mi][ni][2] + bv);
        o.w = f2b(acc[mi][ni][3] + bv);
        *(ushort4*)&((unsigned short*)d.C)[(size_t)col * M + rowb] = o;
      } else {
        #pragma unroll
        for (int r = 0; r < 4; r++) {
          float v = acc[mi][ni][r] + bv;
          if (d.add_in) v += d.add_in[(size_t)(rowb + r) * ldc + col];
          if (OUTBF)
            ((unsigned short*)d.C)[(size_t)(rowb + r) * ldc + col] = f2b(v);
          else
            ((float*)d.C)[(size_t)(rowb + r) * ldc + col] = v;
        }
      }
    }
  }
}

// ---------------------------------------------------------------------------
// FFN1 GEMM with fused GELU: hm = lnA@w1^T + b1, hv = lnB@w1var^T + b1v,
// gelu in epilogue (fp32), writes am/am^2/av bf16.
// ---------------------------------------------------------------------------
__global__ __launch_bounds__(256) void gemm_ffn1(
    const unsigned short* __restrict__ A1, const unsigned short* __restrict__ A2,
    const unsigned short* __restrict__ W1, const unsigned short* __restrict__ W2,
    const float* __restrict__ b1, const float* __restrict__ b2,
    unsigned short* __restrict__ am_o, unsigned short* __restrict__ am2_o,
    unsigned short* __restrict__ av_o)
{
  const int n0 = blockIdx.x * 128;
  const int m0 = blockIdx.y * 64;
  constexpr int K = 512;

  __shared__ short As0[64 * 32], As1[64 * 32];
  __shared__ short Bs0[64 * 32], Bs1[64 * 32];
  __shared__ short Ws0[128 * 32], Ws1[128 * 32];
  __shared__ short Vs0[128 * 32], Vs1[128 * 32];

  const int tid = threadIdx.x;
  const int lane = tid & 63;
  const int wv = tid >> 6;
  const int wr = wv >> 1, wc = wv & 1;
  const int fr = lane & 15;
  const int fk = (lane >> 4) * 8;

  const int rowA = m0 + (tid >> 2);
  const int rowW = n0 + (tid >> 2);
  const int colc = (tid & 3) * 8;
  const unsigned short* gA1 = A1 + (size_t)rowA * K + colc;
  const unsigned short* gA2 = A2 + (size_t)rowA * K + colc;
  const unsigned short* gW1a = W1 + (size_t)rowW * K + colc;
  const unsigned short* gW1b = gW1a + (size_t)64 * K;
  const unsigned short* gW2a = W2 + (size_t)rowW * K + colc;
  const unsigned short* gW2b = gW2a + (size_t)64 * K;

  f32x4 accA[2][4] = {};
  f32x4 accB[2][4] = {};

  uint4 ra0, ra1, rb0, rb1, rw0, rw1, rw2, rw3, rv0, rv1, rv2, rv3;
  ra0 = *(const uint4*)(gA1);      ra1 = *(const uint4*)(gA1 + 32);
  rb0 = *(const uint4*)(gA2);      rb1 = *(const uint4*)(gA2 + 32);
  rw0 = *(const uint4*)(gW1a);     rw1 = *(const uint4*)(gW1a + 32);
  rw2 = *(const uint4*)(gW1b);     rw3 = *(const uint4*)(gW1b + 32);
  rv0 = *(const uint4*)(gW2a);     rv1 = *(const uint4*)(gW2a + 32);
  rv2 = *(const uint4*)(gW2b);     rv3 = *(const uint4*)(gW2b + 32);

  for (int k0 = 0; k0 < K; k0 += 64) {
    __syncthreads();
    *(uint4*)&As0[tid * 8] = ra0;  *(uint4*)&As1[tid * 8] = ra1;
    *(uint4*)&Bs0[tid * 8] = rb0;  *(uint4*)&Bs1[tid * 8] = rb1;
    *(uint4*)&Ws0[tid * 8] = rw0;  *(uint4*)&Ws1[tid * 8] = rw1;
    *(uint4*)&Ws0[(tid + 256) * 8] = rw2;  *(uint4*)&Ws1[(tid + 256) * 8] = rw3;
    *(uint4*)&Vs0[tid * 8] = rv0;  *(uint4*)&Vs1[tid * 8] = rv1;
    *(uint4*)&Vs0[(tid + 256) * 8] = rv2;  *(uint4*)&Vs1[(tid + 256) * 8] = rv3;
    __syncthreads();

    if (k0 + 64 < K) {
      int kn = k0 + 64;
      ra0 = *(const uint4*)(gA1 + kn);  ra1 = *(const uint4*)(gA1 + kn + 32);
      rb0 = *(const uint4*)(gA2 + kn);  rb1 = *(const uint4*)(gA2 + kn + 32);
      rw0 = *(const uint4*)(gW1a + kn); rw1 = *(const uint4*)(gW1a + kn + 32);
      rw2 = *(const uint4*)(gW1b + kn); rw3 = *(const uint4*)(gW1b + kn + 32);
      rv0 = *(const uint4*)(gW2a + kn); rv1 = *(const uint4*)(gW2a + kn + 32);
      rv2 = *(const uint4*)(gW2b + kn); rv3 = *(const uint4*)(gW2b + kn + 32);
    }

    #pragma unroll
    for (int half = 0; half < 2; half++) {
      const short* As = half ? As1 : As0;
      const short* Bs = half ? Bs1 : Bs0;
      const short* Ws = half ? Ws1 : Ws0;
      const short* Vs = half ? Vs1 : Vs0;
      bf16x8 afA[2], afB[2], wf[4], vf[4];
      #pragma unroll
      for (int mi = 0; mi < 2; mi++) {
        afA[mi] = *(const bf16x8*)&As[(wr * 32 + mi * 16 + fr) * 32 + fk];
        afB[mi] = *(const bf16x8*)&Bs[(wr * 32 + mi * 16 + fr) * 32 + fk];
      }
      #pragma unroll
      for (int ni = 0; ni < 4; ni++) {
        wf[ni] = *(const bf16x8*)&Ws[(wc * 64 + ni * 16 + fr) * 32 + fk];
        vf[ni] = *(const bf16x8*)&Vs[(wc * 64 + ni * 16 + fr) * 32 + fk];
      }
      #pragma unroll
      for (int mi = 0; mi < 2; mi++)
        #pragma unroll
        for (int ni = 0; ni < 4; ni++) {
          accA[mi][ni] = __builtin_amdgcn_mfma_f32_16x16x32_bf16(
              afA[mi], wf[ni], accA[mi][ni], 0, 0, 0);
          accB[mi][ni] = __builtin_amdgcn_mfma_f32_16x16x32_bf16(
              afB[mi], vf[ni], accB[mi][ni], 0, 0, 0);
        }
    }
  }

  const int quad = lane >> 4;
  #pragma unroll
  for (int mi = 0; mi < 2; mi++) {
    #pragma unroll
    for (int ni = 0; ni < 4; ni++) {
      int col = n0 + wc * 64 + ni * 16 + fr;
      float bb1 = b1[col], bb2 = b2[col];
      int rowb = m0 + wr * 32 + mi * 16 + quad * 4;
      #pragma unroll
      for (int r = 0; r < 4; r++) {
        float hm = accA[mi][ni][r] + bb1;
        float hv = accB[mi][ni][r] + bb2;
        float phi = 0.5f * (1.f + erff(hm * 0.70710678118654752f));
        float pdf = __expf(-0.5f * hm * hm) * 0.39894228040143268f;
        float am = hm * phi;
        float gd = phi + hm * pdf;
        size_t idx = (size_t)(rowb + r) * DFFx + col;
        am_o[idx] = f2b(am);
        am2_o[idx] = f2b(am * am);
        av_o[idx] = f2b(gd * gd * hv);
      }
    }
  }
}

// ---------------------------------------------------------------------------
// MFMA flash attention (round-8 verbatim): direct exp (libm expf — its VALU
// stream doubles as prefetch-latency cover; do NOT replace with __expf),
// reg-prefetch staging, O^T operand swap, P and P^2 staged through LDS.
// ---------------------------------------------------------------------------
__global__ __launch_bounds__(256) void flash_mfma(
    const unsigned short* __restrict__ QK,
    const unsigned short* __restrict__ VT,
    const unsigned short* __restrict__ rbf,
    unsigned short* __restrict__ ctx_bf, unsigned short* __restrict__ ctxsq_bf,
    float* __restrict__ vta)
{
  const int qt = blockIdx.x, h = blockIdx.y, b = blockIdx.z;
  const int q0 = qt * 64;
  const int tid = threadIdx.x;
  const int w = tid >> 6;
  const int lane = tid & 63;
  const int fr = lane & 15;
  const int quad = lane >> 4;

  __shared__ unsigned short Kt[64 * 72];
  __shared__ unsigned short VtT[64 * 72];
  __shared__ unsigned short VvT[64 * 72];
  __shared__ unsigned short Pt[64 * 72];
  __shared__ unsigned short P2t[64 * 72];
  __shared__ float lred[4][16];

  bf16x8 qa0, qa1;
  {
    const unsigned short* qp =
        QK + ((size_t)(b * Nx + q0 + w * 16 + fr)) * 1024 + h * 64 + quad * 8;
    qa0 = *(const bf16x8*)qp;
    qa1 = *(const bf16x8*)(qp + 32);
  }

  float lsum[4] = {0.f, 0.f, 0.f, 0.f};
  f32x4 accO[4] = {};
  f32x4 accW[4] = {};

  const unsigned short* kg = QK + ((size_t)b * Nx) * 1024 + 512 + h * 64;
  const unsigned short* vg = VT + (size_t)(h * 64) * BN + b * Nx;
  const unsigned short* ug = VT + (size_t)(512 + h * 64) * BN + b * Nx;
  const unsigned short* rb =
      rbf + ((size_t)(h * Bx + b) * Nx + q0 + w * 16 + quad * 4) * Nx;

  const int a0 = tid >> 3;
  const int c8 = (tid & 7) * 8;

  uint4 pk0, pk1, pv0, pv1, pu0, pu1;
  pk0 = *(const uint4*)(kg + (size_t)a0 * 1024 + c8);
  pk1 = *(const uint4*)(kg + (size_t)(a0 + 32) * 1024 + c8);
  pv0 = *(const uint4*)(vg + (size_t)a0 * BN + c8);
  pv1 = *(const uint4*)(vg + (size_t)(a0 + 32) * BN + c8);
  pu0 = *(const uint4*)(ug + (size_t)a0 * BN + c8);
  pu1 = *(const uint4*)(ug + (size_t)(a0 + 32) * BN + c8);

  for (int mt = 0; mt < 16; mt++) {
    __syncthreads();
    *(uint4*)&Kt[a0 * 72 + c8] = pk0;
    *(uint4*)&Kt[(a0 + 32) * 72 + c8] = pk1;
    *(uint4*)&VtT[a0 * 72 + c8] = pv0;
    *(uint4*)&VtT[(a0 + 32) * 72 + c8] = pv1;
    *(uint4*)&VvT[a0 * 72 + c8] = pu0;
    *(uint4*)&VvT[(a0 + 32) * 72 + c8] = pu1;
    __syncthreads();

    if (mt + 1 < 16) {
      const int n1 = (mt + 1) * 64;
      pk0 = *(const uint4*)(kg + (size_t)(n1 + a0) * 1024 + c8);
      pk1 = *(const uint4*)(kg + (size_t)(n1 + a0 + 32) * 1024 + c8);
      pv0 = *(const uint4*)(vg + (size_t)a0 * BN + n1 + c8);
      pv1 = *(const uint4*)(vg + (size_t)(a0 + 32) * BN + n1 + c8);
      pu0 = *(const uint4*)(ug + (size_t)a0 * BN + n1 + c8);
      pu1 = *(const uint4*)(ug + (size_t)(a0 + 32) * BN + n1 + c8);
    }

    f32x4 accS[4] = {};
    #pragma unroll
    for (int ni = 0; ni < 4; ni++) {
      bf16x8 b0 = *(const bf16x8*)&Kt[(ni * 16 + fr) * 72 + quad * 8];
      bf16x8 b1 = *(const bf16x8*)&Kt[(ni * 16 + fr) * 72 + 32 + quad * 8];
      accS[ni] = __builtin_amdgcn_mfma_f32_16x16x32_bf16(qa0, b0, accS[ni], 0, 0, 0);
      accS[ni] = __builtin_amdgcn_mfma_f32_16x16x32_bf16(qa1, b1, accS[ni], 0, 0, 0);
    }

    const int m0 = mt * 64;
    #pragma unroll
    for (int reg = 0; reg < 4; reg++) {
      const unsigned short* rr = rb + (size_t)reg * Nx + m0;
      int rowb = (w * 16 + quad * 4 + reg) * 72;
      #pragma unroll
      for (int ni = 0; ni < 4; ni++) {
        float pv = expf(accS[ni][reg] * 0.125f + b2f(rr[ni * 16 + fr]));
        lsum[reg] += pv;
        Pt[rowb + ni * 16 + fr] = f2b(pv);
        P2t[rowb + ni * 16 + fr] = f2b(pv * pv);
      }
    }
    __syncthreads();

    #pragma unroll
    for (int ks = 0; ks < 2; ks++) {
      bf16x8 pa  = *(const bf16x8*)&Pt[(w * 16 + fr) * 72 + ks * 32 + quad * 8];
      bf16x8 p2a = *(const bf16x8*)&P2t[(w * 16 + fr) * 72 + ks * 32 + quad * 8];
      #pragma unroll
      for (int ni = 0; ni < 4; ni++) {
        bf16x8 vb = *(const bf16x8*)&VtT[(ni * 16 + fr) * 72 + ks * 32 + quad * 8];
        bf16x8 ub = *(const bf16x8*)&VvT[(ni * 16 + fr) * 72 + ks * 32 + quad * 8];
        accO[ni] = __builtin_amdgcn_mfma_f32_16x16x32_bf16(vb, pa, accO[ni], 0, 0, 0);
        accW[ni] = __builtin_amdgcn_mfma_f32_16x16x32_bf16(ub, p2a, accW[ni], 0, 0, 0);
      }
    }
  }

  #pragma unroll
  for (int reg = 0; reg < 4; reg++) {
    float t = lsum[reg];
    t += __shfl_xor(t, 1);
    t += __shfl_xor(t, 2);
    t += __shfl_xor(t, 4);
    t += __shfl_xor(t, 8);
    lsum[reg] = t;
  }
  if (fr == 0) {
    #pragma unroll
    for (int reg = 0; reg < 4; reg++) lred[w][quad * 4 + reg] = lsum[reg];
  }
  __syncthreads();
  float invl = 1.f / lred[w][fr];
  float invl2 = invl * invl;

  size_t row = (size_t)b * Nx + q0 + w * 16 + fr;
  #pragma unroll
  for (int ni = 0; ni < 4; ni++) {
    int dkb = h * 64 + ni * 16 + quad * 4;
    ushort4 oc, oc2;
    float4 ov;
    float c0 = accO[ni][0] * invl, c1 = accO[ni][1] * invl;
    float c2 = accO[ni][2] * invl, c3 = accO[ni][3] * invl;
    oc.x = f2b(c0); oc.y = f2b(c1); oc.z = f2b(c2); oc.w = f2b(c3);
    oc2.x = f2b(c0 * c0); oc2.y = f2b(c1 * c1);
    oc2.z = f2b(c2 * c2); oc2.w = f2b(c3 * c3);
    ov.x = accW[ni][0] * invl2; ov.y = accW[ni][1] * invl2;
    ov.z = accW[ni][2] * invl2; ov.w = accW[ni][3] * invl2;
    *(ushort4*)&ctx_bf[row * Dx + dkb] = oc;
    *(ushort4*)&ctxsq_bf[row * Dx + dkb] = oc2;
    *(float4*)&vta[row * Dx + dkb] = ov;
  }
}

// ---------------------------------------------------------------------------
// combine (x4 vectorized): F = Hb+fm (fused); fva = avar+ovd (fused)
// ---------------------------------------------------------------------------
__global__ __launch_bounds__(256) void combine_k(
    const float* __restrict__ Hin, const float* __restrict__ Hvin,
    float* __restrict__ Hout, float* __restrict__ Hvout,
    const float* __restrict__ F, const float* __restrict__ fva,
    const float* __restrict__ vc, const float* __restrict__ lg)
{
  size_t i = ((size_t)blockIdx.x * 256 + threadIdx.x) * 4;
  float g1 = sp_(lg[0]), g2 = sp_(lg[1]), g3 = sp_(lg[2]), g4 = sp_(lg[3]);
  float s12 = g1 + g2, s34 = g3 + g4;
  float alpha = g1 / s12, beta = g3 / s34;
  float Va = g1 * g2 / (s12 * s12 * (s12 + 1.f));
  float Vb = g3 * g4 / (s34 * s34 * (s34 + 1.f));
  float4 h4 = *(const float4*)&Hin[i];
  float4 hv4 = *(const float4*)&Hvin[i];
  float4 F4 = *(const float4*)&F[i];
  float4 a4 = *(const float4*)&fva[i];
  float4 c4 = *(const float4*)&vc[i];
  float* hp = (float*)&h4; float* vp = (float*)&hv4;
  const float* Fp = (const float*)&F4; const float* ap = (const float*)&a4;
  const float* cp = (const float*)&c4;
  float4 ho, vo;
  float* hop = (float*)&ho; float* vop = (float*)&vo;
  #pragma unroll
  for (int j = 0; j < 4; j++) {
    float h = hp[j], hv = vp[j];
    float Fm = Fp[j];
    float Fv = ap[j] + cp[j];
    hop[j] = alpha * h + beta * Fm;
    vop[j] = alpha * alpha * hv + beta * beta * Fv + Va * h * h + Vb * Fm * Fm +
             Va * hv + Vb * Fv;
  }
  *(float4*)&Hout[i] = ho;
  *(float4*)&Hvout[i] = vo;
}

// ---------------------------------------------------------------------------
// launch
// ---------------------------------------------------------------------------
extern "C" void kernel_launch(void* const* d_in, const int* in_sizes, int n_in,
                              void* d_out, int out_size, void* d_ws, size_t ws_size,
                              hipStream_t stream)
{
  const float* H_in   = (const float*)d_in[0];
  const float* Hv_in  = (const float*)d_in[1];
  const float* x_raw  = (const float*)d_in[2];
  const float* aw_mu  = (const float*)d_in[4];
  const float* aw_rho = (const float*)d_in[5];
  const float* ab_mu  = (const float*)d_in[6];
  const float* ab_rho = (const float*)d_in[7];
  const float* w1_mu  = (const float*)d_in[8];
  const float* w1_rho = (const float*)d_in[9];
  const float* b1_mu  = (const float*)d_in[10];
  const float* b1_rho = (const float*)d_in[11];
  const float* w2_mu  = (const float*)d_in[12];
  const float* w2_rho = (const float*)d_in[13];
  const float* b2_mu  = (const float*)d_in[14];
  const float* b2_rho = (const float*)d_in[15];
  const float* ln1_g  = (const float*)d_in[16];
  const float* ln1_b  = (const float*)d_in[17];
  const float* ln2_g  = (const float*)d_in[18];
  const float* ln2_b  = (const float*)d_in[19];
  const float* lsf    = (const float*)d_in[20];
  const float* lll    = (const float*)d_in[21];
  const float* lgam   = (const float*)d_in[22];

  float* Hout = (float*)d_out;
  float* Hvar = (float*)d_out + BND;

  float* ws = (float*)d_ws;
  size_t off = 0;
  auto allocf = [&](size_t n) {
    float* p = ws + off; off += (n + 7) & ~(size_t)7; return p;
  };
  auto allocus = [&](size_t n) {
    return (unsigned short*)allocf((n + 1) / 2);
  };
  unsigned short* rbf = allocus((size_t)NHx * Bx * Nx * Nx);   // 67 MB
  float* vta = allocf(BND);
  float* Hb  = allocf(BND);
  float* fva = allocf(BND);
  float* vc  = allocf(BND);
  unsigned short* QKb = allocus(BN * 1024);
  unsigned short* VTb = allocus((size_t)1024 * BN);
  unsigned short* lnA = allocus(BND);
  unsigned short* lnB = allocus(BND);
  unsigned short* am_bf  = allocus(BNF);
  unsigned short* am2_bf = allocus(BNF);
  unsigned short* av_bf  = allocus(BNF);
  unsigned short* aw_bf     = allocus(4 * DD);
  unsigned short* wvvar_bf  = allocus(DD);
  unsigned short* wovar_bf  = allocus(DD);
  unsigned short* w1_bf     = allocus(DF);
  unsigned short* w1var_bf  = allocus(DF);
  unsigned short* w2_bf     = allocus(DF);
  unsigned short* w2var_bf  = allocus(DF);
  unsigned short* w2comb_bf = allocus(DF);
  float* bv2 = allocf(512);
  float* bo2 = allocf(512);
  float* b1v = allocf(2048);
  float* b2v = allocf(512);
  float* sqb = allocf(BN);
  (void)ws_size; (void)in_sizes; (void)n_in; (void)out_size;

  {
    int tot = 6 * DD + 3 * DF + 3584 + (int)BN;
    cvt_weights<<<(tot + 255) / 256, 256, 0, stream>>>(
        aw_mu, aw_rho, w1_mu, w1_rho, w2_mu, w2_rho,
        ab_rho, b1_rho, b2_rho, x_raw,
        aw_bf, wvvar_bf, wovar_bf, w1_bf, w1var_bf, w2_bf, w2var_bf,
        w2comb_bf, bv2, bo2, b1v, b2v, sqb);
  }
  gram_rbf<<<dim3(16, 16, Bx), 256, 0, stream>>>(x_raw, sqb, lsf, lll, rbf);

  const int M = (int)BN;
  GD dz = {nullptr, nullptr, nullptr, nullptr, nullptr, 0, 0};

  const float* Hsrc  = H_in;
  const float* Hvsrc = Hv_in;

  for (int t = 0; t < 2; t++) {   // TMAX (early-exit statically dead)
    // ---- attention half ----
    layernorm_bf<<<(int)BN, 256, 0, stream>>>(Hsrc, ln1_g, ln1_b, lnA, lnB);
    {
      GD dqk = {lnA, aw_bf, ab_mu, nullptr, (void*)QKb, 1024, 0};
      GD dv  = {lnA, aw_bf + 2 * (size_t)DD, ab_mu + 1024, nullptr,
                (void*)VTb, 512, 1};
      GD dvv = {lnB, wvvar_bf, bv2, nullptr,
                (void*)(VTb + (size_t)512 * BN), 512, 1};
      gemm_mf<false, true><<<dim3(8, 32, 3), 256, 0, stream>>>(
          dqk, dv, dvv, M, 512, 1024);
    }
    flash_mfma<<<dim3(Nx / 64, NHx, Bx), 256, 0, stream>>>(
        QKb, VTb, rbf, lnA, lnB, vta);
    {
      GD d_om = {lnA, aw_bf + 3 * (size_t)DD, ab_mu + 1536, Hsrc, (void*)Hb,
                 512, 0};
      GD d_ov = {lnB, wovar_bf, bo2, vta, (void*)vta, 512, 0};
      gemm_mf<true, false><<<dim3(4, 64, 2), 256, 0, stream>>>(
          d_om, d_ov, dz, M, 512, 512);
    }

    // ---- FFN half ----
    layernorm_bf<<<(int)BN, 256, 0, stream>>>(Hb, ln2_g, ln2_b, lnA, lnB);
    gemm_ffn1<<<dim3(16, 64), 256, 0, stream>>>(
        lnA, lnB, w1_bf, w1var_bf, b1_mu, b1v, am_bf, am2_bf, av_bf);
    {
      GD d_fm  = {am_bf, w2_bf, b2_mu, Hb, (void*)Hb, 512, 0};    // F = Hb+fm
      GD d_ovd = {am2_bf, w2var_bf, b2v, vta, (void*)fva, 512, 0}; // avar+ovd
      GD d_vc  = {av_bf, w2comb_bf, nullptr, nullptr, (void*)vc, 512, 0};
      gemm_mf<true, false><<<dim3(4, 64, 3), 256, 0, stream>>>(
          d_fm, d_ovd, d_vc, M, 2048, 512);
    }
    combine_k<<<(int)(BND / (256 * 4)), 256, 0, stream>>>(
        Hsrc, Hvsrc, Hout, Hvar, Hb, fva, vc, lgam);

    Hsrc = Hout;
    Hvsrc = Hvar;
  }
}